// Round 16
// baseline (94.742 us; speedup 1.0000x reference)
//
#include <hip/hip_runtime.h>

// LSTM: B=16384, T=1024, I=1, H=2, C=4.
// 2 lanes per batch element: lane (2e+j) owns hidden unit j of element e.
//
// R16 = R15 (verified best: 88.0 us = 206 cy/step) + four more VOP3P packs.
// Validated law (R4..R15): only instruction REMOVALS win; never trade a
// trans stage for VALU links. Each pack below fuses two scalar ops whose
// operands become ready at the SAME time -> no chain link moves:
//  1. {GpF, GmF} = pk_fma({Eg,Eg},{F,F},{F,-F})   (GpF=EgF+F, GmF=EgF-F)
//  2. {B,  cp } = pk_mul({GpF, c}, {Ip,Ip})
//  3. {c,  zc } = pk_mul({A, zA}, {rB,rB})
//  4. {numer,D} = pk_mul({zc, Oo}, {p,q})
// Everything else (4-deep prefetch, exp2 ordering, clamp-before-rcp,
// Pade[5/4], placement 512x64) byte-identical to R15.
//
// Gate rows (PyTorch order): i: 0,1  f: 2,3  g: 4,5  o: 6,7
//   Ei=e^-i, Ef=e^-f, Eo=e^-o (SIG_SCALE folded), Eg=e^{2g} (TANH_SCALE).
//   c' = A/B:  A = (c*Ip)*Gp + (Eg-1)*F,  B = (Gp*F)*Ip,
//   F=1+Ef, Ip=1+Ei, Gp=1+Eg, Oo=1+Eo.
//   h' = tanh(zc)*sigma(o), zc = med3(A,-4B,4B)*rB,
//   tanh(zc) = zc*(zc^4+105zc^2+945)/(15zc^4+420zc^2+945),  D = q*Oo.

typedef float f32x2 __attribute__((ext_vector_type(2)));

static __device__ __forceinline__ float fast_exp2(float x) { return __builtin_amdgcn_exp2f(x); }
static __device__ __forceinline__ float fast_rcp(float x)  { return __builtin_amdgcn_rcpf(x); }

// Swap values between lane pairs (0<->1, 2<->3, ...) via DPP quad_perm.
static __device__ __forceinline__ float dpp_swap1(float v) {
    int i = __builtin_bit_cast(int, v);
    i = __builtin_amdgcn_mov_dpp(i, 0xB1, 0xF, 0xF, false);
    return __builtin_bit_cast(float, i);
}

#define SIG_SCALE  (-1.4426950408889634f)  // -log2(e)
#define TANH_SCALE ( 2.8853900817779268f)  // 2*log2(e)

__global__ __launch_bounds__(64, 1) void lstm_fused12(
    const float* __restrict__ x,      // [B, T, 1]
    const float* __restrict__ W_ih,   // [8, 1]
    const float* __restrict__ W_hh,   // [8, 2]
    const float* __restrict__ b_ih,   // [8]
    const float* __restrict__ b_hh,   // [8]
    const float* __restrict__ W_fc,   // [4, 2]
    const float* __restrict__ b_fc,   // [4]
    float* __restrict__ out,          // [B, 4]
    int T)
{
    const int tid = blockIdx.x * 64 + threadIdx.x;
    const int e   = tid >> 1;          // batch element
    const int j   = tid & 1;           // hidden unit owned by this lane

    // Per-lane scaled weights for my unit's 4 gates (k: 0=i,1=f,2=g,3=o).
    // whm multiplies MY h, whp multiplies my PARTNER's h.
    float wihs[4], whm[4], whp[4], bbs[4];
#pragma unroll
    for (int k = 0; k < 4; ++k) {
        const int g = 2 * k + j;                         // gate row
        const float s = (k == 2) ? TANH_SCALE : SIG_SCALE;
        wihs[k] = s * W_ih[g];
        whm[k]  = s * W_hh[2 * g + j];
        whp[k]  = s * W_hh[2 * g + (j ^ 1)];
        bbs[k]  = s * (b_ih[g] + b_hh[g]);
    }

    // Packed views for v_pk_fma_f32 on the pre-activation math.
    f32x2 wihs2[2], whm2[2], whp2[2], bbs2[2];
#pragma unroll
    for (int q = 0; q < 2; ++q) {
        wihs2[q] = f32x2{wihs[2*q], wihs[2*q+1]};
        whm2[q]  = f32x2{whm[2*q],  whm[2*q+1]};
        whp2[q]  = f32x2{whp[2*q],  whp[2*q+1]};
        bbs2[q]  = f32x2{bbs[2*q],  bbs[2*q+1]};
    }

    // Hoisted VOP3P constant vectors (loop-invariant registers).
    const f32x2 one2    = {1.f, 1.f};
    const f32x2 pq_hi   = {1.f, 15.f};     // leading coeffs of p,q
    const f32x2 pq_mid  = {105.f, 420.f};  // middle coeffs
    const f32x2 pq_lo   = {945.f, 945.f};  // constant terms

    float hm = 0.f;   // my unit's h
    float hp = 0.f;   // partner unit's h
    float c  = 0.f;   // my unit's c

    const float4* xv = reinterpret_cast<const float4*>(x + (size_t)e * (size_t)T);
    const int nt4 = T >> 2;            // 256 groups of 4 timesteps

    // 4-deep rotating prefetch pipeline (static slots — no dynamic indexing).
    float4 slot0 = xv[0];
    float4 slot1 = xv[1];
    float4 slot2 = xv[2];
    float4 slot3 = xv[3];

    const int nblk = nt4 >> 2;         // 64 blocks of 4 groups

    for (int bg = 0; bg < nblk; ++bg) {
        const int g0 = bg << 2;

#pragma unroll
        for (int i = 0; i < 4; ++i) {
            // Consume slot i (group g0+i), then re-issue its load for
            // group g0+i+4 (clamped): ~12 steps in flight > HBM latency.
            float4 xq = (i == 0) ? slot0 : (i == 1) ? slot1 : (i == 2) ? slot2 : slot3;

            const int gn = g0 + i + 4;
            const int gl = (gn < nt4) ? gn : (nt4 - 1);    // uniform clamp
            const float4 nx = xv[gl];
            if (i == 0) slot0 = nx; else if (i == 1) slot1 = nx;
            else if (i == 2) slot2 = nx; else slot3 = nx;

            const float xs[4] = {xq.x, xq.y, xq.z, xq.w};

            // h-independent x-terms for 4 timesteps (packed fma, off-chain).
            f32x2 xterm[4][2];
#pragma unroll
            for (int u = 0; u < 4; ++u) {
                const f32x2 xu = f32x2{xs[u], xs[u]};
#pragma unroll
                for (int q = 0; q < 2; ++q)
                    xterm[u][q] = __builtin_elementwise_fma(xu, wihs2[q], bbs2[q]);
            }

#pragma unroll
            for (int u = 0; u < 4; ++u) {
                const f32x2 hmv = f32x2{hm, hm};
                const f32x2 hpv = f32x2{hp, hp};
                // hm-term first (hm ready before DPP delivers hp).
                const f32x2 in23 = __builtin_elementwise_fma(whm2[1], hmv, xterm[u][1]);
                const f32x2 in01 = __builtin_elementwise_fma(whm2[0], hmv, xterm[u][0]);
                const f32x2 pre23 = __builtin_elementwise_fma(whp2[1], hpv, in23);
                const f32x2 pre01 = __builtin_elementwise_fma(whp2[0], hpv, in01);

                // Chain-critical exps first: Eg, Ef, Ei; Eo has slack.
                const float Eg = fast_exp2(pre23.x);
                const float Ef = fast_exp2(pre01.y);
                const float Ei = fast_exp2(pre01.x);
                const float Eo = fast_exp2(pre23.y);

                // Packed (1+E): {Ip,F} and {Gp,Oo}.
                const f32x2 E01 = {Ei, Ef};
                const f32x2 E23 = {Eg, Eo};
                const f32x2 P01 = E01 + one2;   // {Ip, F}
                const f32x2 P23 = E23 + one2;   // {Gp, Oo}
                const float Ip = P01.x, F = P01.y, Gp = P23.x, Oo = P23.y;

                // Pack 1: {GpF, GmF} = {Eg*F+F, Eg*F-F}.
                const f32x2 GF = __builtin_elementwise_fma(
                    f32x2{Eg, Eg}, f32x2{F, F}, f32x2{F, -F});

                // Pack 2: {B, cp} = {GpF*Ip, c*Ip}.
                const f32x2 Bcp = f32x2{GF.x, c} * f32x2{Ip, Ip};
                const float B  = Bcp.x;
                const float A  = fmaf(Bcp.y, Gp, GF.y);        // cp*Gp + GmF

                // Clamp in (A,B) space BEFORE the rcp (issues during rcp wait).
                const float B4 = 4.0f * B;
                const float zA = __builtin_amdgcn_fmed3f(A, -B4, B4);

                const float rB = fast_rcp(B);                  // trans stage 2

                // Pack 3: {c, zc} = {A*rB, zA*rB}.
                const f32x2 czc = f32x2{A, zA} * f32x2{rB, rB};
                c = czc.x;                                     // next cell, off-path
                const float zc = czc.y;                        // clamped c'

                // Pade[5/4] tanh, p & q packed: {p,q} in 2 pk_fma.
                const float uu = zc * zc;
                const f32x2 uu2 = {uu, uu};
                const f32x2 pq_in = __builtin_elementwise_fma(pq_hi, uu2, pq_mid);
                const f32x2 pq    = __builtin_elementwise_fma(pq_in, uu2, pq_lo);

                // Pack 4: {numer, D} = {zc*p, Oo*q}.
                const f32x2 nD = f32x2{zc, Oo} * pq;
                const float rD = fast_rcp(nD.y);               // trans stage 3
                hm = nD.x * rD;                                // tanh(c')*sigma(o)

                hp = dpp_swap1(hm);                            // lane-pair swap
            }
        }
    }

    // Final FC: out[e,:] = h @ W_fc^T + b_fc.  Even lane -> classes 0,1;
    // odd lane -> classes 2,3. Lane pair writes one contiguous 16B row.
    const float h0 = j ? hp : hm;
    const float h1 = j ? hm : hp;
    const int   c0 = 2 * j;
    const float o0 = fmaf(W_fc[2*c0+0], h0, fmaf(W_fc[2*c0+1], h1, b_fc[c0]));
    const float o1 = fmaf(W_fc[2*c0+2], h0, fmaf(W_fc[2*c0+3], h1, b_fc[c0+1]));
    float2 r2; r2.x = o0; r2.y = o1;
    reinterpret_cast<float2*>(out)[e * 2 + j] = r2;
}

extern "C" void kernel_launch(void* const* d_in, const int* in_sizes, int n_in,
                              void* d_out, int out_size, void* d_ws, size_t ws_size,
                              hipStream_t stream) {
    const float* x    = (const float*)d_in[0];
    const float* W_ih = (const float*)d_in[1];
    const float* W_hh = (const float*)d_in[2];
    const float* b_ih = (const float*)d_in[3];
    const float* b_hh = (const float*)d_in[4];
    const float* W_fc = (const float*)d_in[5];
    const float* b_fc = (const float*)d_in[6];
    float* out = (float*)d_out;

    const int T = 1024;
    const int B = in_sizes[0] / T;   // I == 1

    dim3 block(64);
    dim3 grid((B * 2) / 64);         // 512 waves -> 2 waves/CU (R10 placement)
    lstm_fused12<<<grid, block, 0, stream>>>(x, W_ih, W_hh, b_ih, b_hh, W_fc, b_fc, out, T);
}

// Round 17
// 86.129 us; speedup vs baseline: 1.1000x; 1.1000x over previous
//
#include <hip/hip_runtime.h>

// LSTM: B=16384, T=1024, I=1, H=2, C=4.
// 2 lanes per batch element: lane (2e+j) owns hidden unit j of element e.
//
// R17 = R15 (verified best: 88.0 us = 206 cy/step) + ONE algebraic removal:
//   W = Ip*Gp;  B = F*W;  A = fmaf(c, W, GmF)
// replaces {GpF=Gp*F, B=GpF*Ip, cp=c*Ip, A=fmaf(cp,Gp,GmF)}: 5 ops -> 4,
// same chain depth (B and A both at exp2+12). R16's cross-pair VOP3P packs
// REVERTED (they forced reg-pair marshaling movs onto the chain: +16 cy).
//
// Validated cost model (fits R13/R15/R16 +-3cy): 206 cy/step =
//   chain{dpp 8 + 2 pre-fma 8 + exp2 ~45 + links ~20 + rcp ~45 +
//         zc/uu/pq/D ~24 + rcp ~45 + mul 4} + ~7 issue overflow.
// This is a LATENCY floor (serial 1024-step recurrence; VALUBusy 28%,
// HBM 4%): no throughput pipe is near saturation. Trans-elimination
// trades failed 3x (R8/R11/R14); placement fails (R12); cross-pair
// packing fails (R16). Only already-paired VOP3P + pure removals win.
//
// Gate rows (PyTorch order): i: 0,1  f: 2,3  g: 4,5  o: 6,7
//   Ei=e^-i, Ef=e^-f, Eo=e^-o (SIG_SCALE folded), Eg=e^{2g} (TANH_SCALE).
//   c' = A/B:  A = c*(Ip*Gp) + (Eg-1)*F,  B = F*(Ip*Gp),
//   F=1+Ef, Ip=1+Ei, Gp=1+Eg, Oo=1+Eo.
//   h' = tanh(zc)*sigma(o), zc = med3(A,-4B,4B)*rB,
//   tanh(zc) = zc*(zc^4+105zc^2+945)/(15zc^4+420zc^2+945),  D = q*Oo.

typedef float f32x2 __attribute__((ext_vector_type(2)));

static __device__ __forceinline__ float fast_exp2(float x) { return __builtin_amdgcn_exp2f(x); }
static __device__ __forceinline__ float fast_rcp(float x)  { return __builtin_amdgcn_rcpf(x); }

// Swap values between lane pairs (0<->1, 2<->3, ...) via DPP quad_perm.
static __device__ __forceinline__ float dpp_swap1(float v) {
    int i = __builtin_bit_cast(int, v);
    i = __builtin_amdgcn_mov_dpp(i, 0xB1, 0xF, 0xF, false);
    return __builtin_bit_cast(float, i);
}

#define SIG_SCALE  (-1.4426950408889634f)  // -log2(e)
#define TANH_SCALE ( 2.8853900817779268f)  // 2*log2(e)

__global__ __launch_bounds__(64, 1) void lstm_fused13(
    const float* __restrict__ x,      // [B, T, 1]
    const float* __restrict__ W_ih,   // [8, 1]
    const float* __restrict__ W_hh,   // [8, 2]
    const float* __restrict__ b_ih,   // [8]
    const float* __restrict__ b_hh,   // [8]
    const float* __restrict__ W_fc,   // [4, 2]
    const float* __restrict__ b_fc,   // [4]
    float* __restrict__ out,          // [B, 4]
    int T)
{
    const int tid = blockIdx.x * 64 + threadIdx.x;
    const int e   = tid >> 1;          // batch element
    const int j   = tid & 1;           // hidden unit owned by this lane

    // Per-lane scaled weights for my unit's 4 gates (k: 0=i,1=f,2=g,3=o).
    // whm multiplies MY h, whp multiplies my PARTNER's h.
    float wihs[4], whm[4], whp[4], bbs[4];
#pragma unroll
    for (int k = 0; k < 4; ++k) {
        const int g = 2 * k + j;                         // gate row
        const float s = (k == 2) ? TANH_SCALE : SIG_SCALE;
        wihs[k] = s * W_ih[g];
        whm[k]  = s * W_hh[2 * g + j];
        whp[k]  = s * W_hh[2 * g + (j ^ 1)];
        bbs[k]  = s * (b_ih[g] + b_hh[g]);
    }

    // Packed views for v_pk_fma_f32 on the pre-activation math.
    f32x2 wihs2[2], whm2[2], whp2[2], bbs2[2];
#pragma unroll
    for (int q = 0; q < 2; ++q) {
        wihs2[q] = f32x2{wihs[2*q], wihs[2*q+1]};
        whm2[q]  = f32x2{whm[2*q],  whm[2*q+1]};
        whp2[q]  = f32x2{whp[2*q],  whp[2*q+1]};
        bbs2[q]  = f32x2{bbs[2*q],  bbs[2*q+1]};
    }

    // Hoisted VOP3P constant vectors (loop-invariant registers).
    const f32x2 one2    = {1.f, 1.f};
    const f32x2 pq_hi   = {1.f, 15.f};     // leading coeffs of p,q
    const f32x2 pq_mid  = {105.f, 420.f};  // middle coeffs
    const f32x2 pq_lo   = {945.f, 945.f};  // constant terms

    float hm = 0.f;   // my unit's h
    float hp = 0.f;   // partner unit's h
    float c  = 0.f;   // my unit's c

    const float4* xv = reinterpret_cast<const float4*>(x + (size_t)e * (size_t)T);
    const int nt4 = T >> 2;            // 256 groups of 4 timesteps

    // 4-deep rotating prefetch pipeline (static slots — no dynamic indexing).
    float4 slot0 = xv[0];
    float4 slot1 = xv[1];
    float4 slot2 = xv[2];
    float4 slot3 = xv[3];

    const int nblk = nt4 >> 2;         // 64 blocks of 4 groups

    for (int bg = 0; bg < nblk; ++bg) {
        const int g0 = bg << 2;

#pragma unroll
        for (int i = 0; i < 4; ++i) {
            // Consume slot i (group g0+i), then re-issue its load for
            // group g0+i+4 (clamped): ~12 steps in flight > HBM latency.
            float4 xq = (i == 0) ? slot0 : (i == 1) ? slot1 : (i == 2) ? slot2 : slot3;

            const int gn = g0 + i + 4;
            const int gl = (gn < nt4) ? gn : (nt4 - 1);    // uniform clamp
            const float4 nx = xv[gl];
            if (i == 0) slot0 = nx; else if (i == 1) slot1 = nx;
            else if (i == 2) slot2 = nx; else slot3 = nx;

            const float xs[4] = {xq.x, xq.y, xq.z, xq.w};

            // h-independent x-terms for 4 timesteps (packed fma, off-chain).
            f32x2 xterm[4][2];
#pragma unroll
            for (int u = 0; u < 4; ++u) {
                const f32x2 xu = f32x2{xs[u], xs[u]};
#pragma unroll
                for (int q = 0; q < 2; ++q)
                    xterm[u][q] = __builtin_elementwise_fma(xu, wihs2[q], bbs2[q]);
            }

#pragma unroll
            for (int u = 0; u < 4; ++u) {
                const f32x2 hmv = f32x2{hm, hm};
                const f32x2 hpv = f32x2{hp, hp};
                // hm-term first (hm ready before DPP delivers hp).
                const f32x2 in23 = __builtin_elementwise_fma(whm2[1], hmv, xterm[u][1]);
                const f32x2 in01 = __builtin_elementwise_fma(whm2[0], hmv, xterm[u][0]);
                const f32x2 pre23 = __builtin_elementwise_fma(whp2[1], hpv, in23);
                const f32x2 pre01 = __builtin_elementwise_fma(whp2[0], hpv, in01);

                // Chain-critical exps first: Eg, Ef, Ei; Eo has slack.
                const float Eg = fast_exp2(pre23.x);
                const float Ef = fast_exp2(pre01.y);
                const float Ei = fast_exp2(pre01.x);
                const float Eo = fast_exp2(pre23.y);

                // Packed (1+E): E01={Ei,Ef}, E23={Eg,Eo}.
                const f32x2 E01 = {Ei, Ef};
                const f32x2 E23 = {Eg, Eo};
                const f32x2 P01 = E01 + one2;   // {Ip, F}
                const f32x2 P23 = E23 + one2;   // {Gp, Oo}
                const float Ip = P01.x, F = P01.y, Gp = P23.x, Oo = P23.y;

                // A = c*W + (Eg-1)F,  B = F*W,  W = Ip*Gp  (4 ops, was 5).
                const float W   = Ip * Gp;
                const float GmF = fmaf(Eg, F, -F);             // (Eg-1)(1+Ef)
                const float B   = F * W;
                const float A   = fmaf(c, W, GmF);

                // Clamp in (A,B) space BEFORE the rcp (issues during rcp wait).
                const float B4  = 4.0f * B;
                const float zA  = __builtin_amdgcn_fmed3f(A, -B4, B4);

                const float rB  = fast_rcp(B);                 // trans stage 2
                c = A * rB;                                    // next cell, off-path
                const float zc = zA * rB;                      // clamped c'

                // Pade[5/4] tanh, p & q packed: {p,q} in 2 pk_fma.
                const float uu = zc * zc;
                const f32x2 uu2 = {uu, uu};
                const f32x2 pq_in = __builtin_elementwise_fma(pq_hi, uu2, pq_mid);
                const f32x2 pq    = __builtin_elementwise_fma(pq_in, uu2, pq_lo);

                const float numer = zc * pq.x;
                const float D  = pq.y * Oo;
                const float rD = fast_rcp(D);                  // trans stage 3
                hm = numer * rD;                               // tanh(c')*sigma(o)

                hp = dpp_swap1(hm);                            // lane-pair swap
            }
        }
    }

    // Final FC: out[e,:] = h @ W_fc^T + b_fc.  Even lane -> classes 0,1;
    // odd lane -> classes 2,3. Lane pair writes one contiguous 16B row.
    const float h0 = j ? hp : hm;
    const float h1 = j ? hm : hp;
    const int   c0 = 2 * j;
    const float o0 = fmaf(W_fc[2*c0+0], h0, fmaf(W_fc[2*c0+1], h1, b_fc[c0]));
    const float o1 = fmaf(W_fc[2*c0+2], h0, fmaf(W_fc[2*c0+3], h1, b_fc[c0+1]));
    float2 r2; r2.x = o0; r2.y = o1;
    reinterpret_cast<float2*>(out)[e * 2 + j] = r2;
}

extern "C" void kernel_launch(void* const* d_in, const int* in_sizes, int n_in,
                              void* d_out, int out_size, void* d_ws, size_t ws_size,
                              hipStream_t stream) {
    const float* x    = (const float*)d_in[0];
    const float* W_ih = (const float*)d_in[1];
    const float* W_hh = (const float*)d_in[2];
    const float* b_ih = (const float*)d_in[3];
    const float* b_hh = (const float*)d_in[4];
    const float* W_fc = (const float*)d_in[5];
    const float* b_fc = (const float*)d_in[6];
    float* out = (float*)d_out;

    const int T = 1024;
    const int B = in_sizes[0] / T;   // I == 1

    dim3 block(64);
    dim3 grid((B * 2) / 64);         // 512 waves -> 2 waves/CU (R10 placement)
    lstm_fused13<<<grid, block, 0, stream>>>(x, W_ih, W_hh, b_ih, b_hh, W_fc, b_fc, out, T);
}